// Round 6
// baseline (256.093 us; speedup 1.0000x reference)
//
#include <hip/hip_runtime.h>

#define HID 128
#define BM 128
#define NT 512
#define TPB 4                 // row-tiles per block
#define GRPS 16               // 8192 / (TPB*BM)
#define NNET 92
#define NBLK (NNET * GRPS)    // 1472, %8==0 -> bijective XCD swizzle
#define LOG2E 1.44269504f

typedef _Float16 f16;
typedef _Float16 f16x2 __attribute__((ext_vector_type(2)));
typedef _Float16 f16x4 __attribute__((ext_vector_type(4)));
typedef _Float16 f16x8 __attribute__((ext_vector_type(8)));
typedef float f32x4 __attribute__((ext_vector_type(4)));

// variable indices per network: 8 singles, 28 pairs, 56 trips (lexicographic)
__constant__ signed char VARS_C[NNET][3] = {
  {0,-1,-1},{1,-1,-1},{2,-1,-1},{3,-1,-1},{4,-1,-1},{5,-1,-1},{6,-1,-1},{7,-1,-1},
  {0,1,-1},{0,2,-1},{0,3,-1},{0,4,-1},{0,5,-1},{0,6,-1},{0,7,-1},
  {1,2,-1},{1,3,-1},{1,4,-1},{1,5,-1},{1,6,-1},{1,7,-1},
  {2,3,-1},{2,4,-1},{2,5,-1},{2,6,-1},{2,7,-1},
  {3,4,-1},{3,5,-1},{3,6,-1},{3,7,-1},
  {4,5,-1},{4,6,-1},{4,7,-1},
  {5,6,-1},{5,7,-1},
  {6,7,-1},
  {0,1,2},{0,1,3},{0,1,4},{0,1,5},{0,1,6},{0,1,7},
  {0,2,3},{0,2,4},{0,2,5},{0,2,6},{0,2,7},
  {0,3,4},{0,3,5},{0,3,6},{0,3,7},
  {0,4,5},{0,4,6},{0,4,7},
  {0,5,6},{0,5,7},
  {0,6,7},
  {1,2,3},{1,2,4},{1,2,5},{1,2,6},{1,2,7},
  {1,3,4},{1,3,5},{1,3,6},{1,3,7},
  {1,4,5},{1,4,6},{1,4,7},
  {1,5,6},{1,5,7},
  {1,6,7},
  {2,3,4},{2,3,5},{2,3,6},{2,3,7},
  {2,4,5},{2,4,6},{2,4,7},
  {2,5,6},{2,5,7},
  {2,6,7},
  {3,4,5},{3,4,6},{3,4,7},
  {3,5,6},{3,5,7},
  {3,6,7},
  {4,5,6},{4,5,7},
  {4,6,7},
  {5,6,7}
};

// final = -35*f0 + sum_n COEF[n] * g_n
__constant__ float COEF_C[NNET] = {
  120.f, 15.f, 15.f, -6.f, -6.f, -6.f, -6.f, -6.f,
  -20.f,-20.f,-20.f,-20.f,-20.f,-20.f,-20.f,-20.f,
  1.f,1.f,1.f,1.f,1.f,1.f,1.f,1.f,1.f,1.f,
  1.f,1.f,1.f,1.f,1.f,1.f,1.f,1.f,1.f,1.f,
  1.f,1.f,1.f,1.f,1.f,1.f,1.f,1.f,1.f,1.f,
  1.f,1.f,1.f,1.f,1.f,1.f,1.f,1.f,1.f,1.f,
  1.f,1.f,1.f,1.f,1.f,1.f,1.f,1.f,1.f,1.f,
  1.f,1.f,1.f,1.f,1.f,1.f,1.f,1.f,1.f,1.f,
  1.f,1.f,1.f,1.f,1.f,1.f,1.f,1.f,1.f,1.f,
  1.f,1.f
};

// s is already -log2e * (pre-activation)  ->  sigmoid = 1/(1+2^s)
__device__ __forceinline__ float sig2(float s) {
    return __builtin_amdgcn_rcpf(1.0f + __builtin_amdgcn_exp2f(s));
}

// XOR-swizzled byte offset into a [row][128] f16 tile (row stride 256 B).
__device__ __forceinline__ int actoff(int row, int colbyte) {
    return row * 256 + (colbyte ^ ((row & 7) << 4));
}

// ---- pre-pass: W_h scaled by -log2e -> f16; W_out -> f16 (unscaled) ----
#define SW 3014656          // 92 * 2*128*128
#define SO1 1024            // 8*128
#define SO2 3584            // 28*128
#define SO3 7168            // 56*128
#define CVT_TOTAL (SW + SO1 + SO2 + SO3)
__global__ __launch_bounds__(256)
void cvt_w(const float* __restrict__ Wh1, const float* __restrict__ Wh2,
           const float* __restrict__ Wh3, const float* __restrict__ Wo1,
           const float* __restrict__ Wo2, const float* __restrict__ Wo3,
           f16* __restrict__ dst) {
    const int i = (blockIdx.x * 256 + threadIdx.x) * 4;
    if (i >= CVT_TOTAL) return;
    float scale;
    const float* s;
    if (i < SW) {           // hidden weights, scaled (group sizes all %4==0)
        scale = -LOG2E;
        if (i < 262144)         s = Wh1 + i;
        else if (i < 1179648)   s = Wh2 + (i - 262144);
        else                    s = Wh3 + (i - 1179648);
    } else {                // output weights, unscaled
        scale = 1.0f;
        int j = i - SW;
        if (j < SO1)            s = Wo1 + j;
        else if (j < SO1 + SO2) s = Wo2 + (j - SO1);
        else                    s = Wo3 + (j - SO1 - SO2);
    }
    float4 v = *(const float4*)s;
    f16x4 h = { (f16)(scale*v.x), (f16)(scale*v.y), (f16)(scale*v.z), (f16)(scale*v.w) };
    *(f16x4*)(dst + i) = h;
}

__global__ __launch_bounds__(NT, 4)   // <=128 VGPR -> 2 blocks/CU (LDS-bound)
void hdmr_fused(const float* __restrict__ x, const float* __restrict__ f0p,
    const float* __restrict__ Wi1, const float* __restrict__ bi1,
    const float* __restrict__ bh1, const float* __restrict__ bo1,
    const float* __restrict__ Wi2, const float* __restrict__ bi2,
    const float* __restrict__ bh2, const float* __restrict__ bo2,
    const float* __restrict__ Wi3, const float* __restrict__ bi3,
    const float* __restrict__ bh3, const float* __restrict__ bo3,
    const f16* __restrict__ Whf, const f16* __restrict__ WoF,
    float* __restrict__ out)
{
    __shared__ __attribute__((aligned(16))) char actb[2][BM * HID * 2]; // 64KB ping-pong
    __shared__ __attribute__((aligned(16))) float xr[2][BM * 8];        // 8KB raw x tiles

    const int tid = threadIdx.x;
    const int bid = blockIdx.x;
    const int swz = (bid & 7) * (NBLK / 8) + (bid >> 3);   // bijective XCD swizzle
    const int N = swz >> 4;            // network id 0..91
    const int grp = swz & (GRPS - 1);
    const int m_base = grp * (TPB * BM);

    int din, lidx;
    const float *Wi, *bi, *bh, *bo;
    if (N < 8)       { lidx = N;      din = 1; Wi=Wi1; bi=bi1; bh=bh1; bo=bo1; }
    else if (N < 36) { lidx = N - 8;  din = 2; Wi=Wi2; bi=bi2; bh=bh2; bo=bo2; }
    else             { lidx = N - 36; din = 3; Wi=Wi3; bi=bi3; bh=bh3; bo=bo3; }
    Wi += (size_t)lidx * HID * din;
    bi += (size_t)lidx * HID;
    bh += (size_t)lidx * 2 * HID;
    const float bout = bo[lidx];
    const float coef = COEF_C[N];
    const float f0c = (N == 0) ? 35.0f * f0p[0] : 0.0f;
    const f16* WN = Whf + (size_t)N * (2 * HID * HID);

    const int lane = tid & 63;
    const int wv = tid >> 6;           // 8 waves
    const int lr = lane & 15;
    const int lk = lane >> 4;          // 0..3
    const int C0 = wv * 16;            // this wave's 16-col (j) slice; also its 16-row band

    // ---- permanent register state: hidden/output weight fragments ----
    f16x8 wA0[4], wA1[4], wOut[4];
    #pragma unroll
    for (int kt = 0; kt < 4; ++kt) {
        wA0[kt] = *(const f16x8*)(WN + (size_t)(C0 + lr) * HID + kt * 32 + lk * 8);
        wA1[kt] = *(const f16x8*)(WN + HID * HID + (size_t)(C0 + lr) * HID + kt * 32 + lk * 8);
        wOut[kt] = *(const f16x8*)(WoF + (size_t)N * HID + kt * 32 + lk * 8);
    }
    f32x4 bias0 = *(const f32x4*)(bh + C0 + lk * 4);
    f32x4 bias1 = *(const f32x4*)(bh + HID + C0 + lk * 4);
    #pragma unroll
    for (int i = 0; i < 4; ++i) { bias0[i] *= -LOG2E; bias1[i] *= -LOG2E; }

    // ---- per-lane input-layer weights in REGISTERS (cols cA=lane*2, cB=lane*2+1) ----
    const int cA = lane * 2, cB = cA + 1;
    float wiA0, wiA1 = 0.f, wiA2 = 0.f, wiB0, wiB1 = 0.f, wiB2 = 0.f;
    wiA0 = -LOG2E * Wi[cA * din];
    wiB0 = -LOG2E * Wi[cB * din];
    if (din > 1) { wiA1 = -LOG2E * Wi[cA * din + 1]; wiB1 = -LOG2E * Wi[cB * din + 1]; }
    if (din > 2) { wiA2 = -LOG2E * Wi[cA * din + 2]; wiB2 = -LOG2E * Wi[cB * din + 2]; }
    const float biA = -LOG2E * bi[cA];
    const float biB = -LOG2E * bi[cB];

    const int v0 = VARS_C[N][0];
    const int v1 = VARS_C[N][1] < 0 ? 0 : VARS_C[N][1];
    const int v2 = VARS_C[N][2] < 0 ? 0 : VARS_C[N][2];

    // ---- stage first x tile ----
    if (tid < 256)
        ((float4*)xr[0])[tid] = ((const float4*)(x + (size_t)m_base * 8))[tid];
    __syncthreads();

    f32x4 acc[8];

    for (int t = 0; t < TPB; ++t) {
        const int p = t & 1;
        // ======== phase A: output MFMA for tile t-1 (buf p^1) + input layer t (buf p) ========
        f32x4 acco = (f32x4){0.f, 0.f, 0.f, 0.f};
        if (t > 0) {
            #pragma unroll
            for (int kt = 0; kt < 4; ++kt) {
                f16x8 bfr = *(const f16x8*)(actb[p ^ 1] + actoff(C0 + lr, (kt * 32 + lk * 8) * 2));
                acco = __builtin_amdgcn_mfma_f32_16x16x32_f16(wOut[kt], bfr, acco, 0, 0, 0);
            }
        }
        {   // input layer: row-uniform iteration over this wave's 16-row band;
            // lanes cover cols lane*2..+1 -> contiguous 256B LDS write, conflict-free
            #pragma unroll
            for (int rr = 0; rr < 16; ++rr) {
                const int row = C0 + rr;
                const float* xrow = &xr[p][row * 8];      // uniform addr -> broadcast
                const float x0 = xrow[v0];
                float sA = biA + x0 * wiA0, sB = biB + x0 * wiB0;
                if (din > 1) { const float x1 = xrow[v1]; sA += x1 * wiA1; sB += x1 * wiB1; }
                if (din > 2) { const float x2 = xrow[v2]; sA += x2 * wiA2; sB += x2 * wiB2; }
                f16x2 hv = { (f16)sig2(sA), (f16)sig2(sB) };
                *(f16x2*)(actb[p] + actoff(row, lane * 4)) = hv;
            }
        }
        if (t > 0 && lk == 0) {
            // D[j][m]: wout replicated over j -> every lane holds out[m=lr]; lanes lk==0 commit
            atomicAdd(&out[m_base + (t - 1) * BM + C0 + lr], coef * (acco[0] + bout) - f0c);
        }
        __syncthreads();

        // ======== hidden layer 0: buf p -> buf p^1 ========
        #pragma unroll
        for (int mt = 0; mt < 8; ++mt) acc[mt] = bias0;
        #pragma unroll
        for (int kt = 0; kt < 4; ++kt) {
            const int kb = (kt * 32 + lk * 8) * 2;
            #pragma unroll
            for (int mh = 0; mh < 2; ++mh) {   // halves to limit live bfr regs
                f16x8 bfr[4];
                #pragma unroll
                for (int mi = 0; mi < 4; ++mi)
                    bfr[mi] = *(const f16x8*)(actb[p] + actoff((mh * 4 + mi) * 16 + lr, kb));
                #pragma unroll
                for (int mi = 0; mi < 4; ++mi)
                    acc[mh * 4 + mi] = __builtin_amdgcn_mfma_f32_16x16x32_f16(wA0[kt], bfr[mi], acc[mh * 4 + mi], 0, 0, 0);
            }
        }
        // prefetch next x tile (waves 0-3) while MFMAs drain
        if (t + 1 < TPB && tid < 256)
            ((float4*)xr[p ^ 1])[tid] = ((const float4*)(x + (size_t)(m_base + (t + 1) * BM) * 8))[tid];
        #pragma unroll
        for (int mt = 0; mt < 8; ++mt) {
            f16x4 hv;
            #pragma unroll
            for (int i = 0; i < 4; ++i) hv[i] = (f16)sig2(acc[mt][i]);
            *(f16x4*)(actb[p ^ 1] + actoff(mt * 16 + lr, (C0 + lk * 4) * 2)) = hv;
        }
        __syncthreads();

        // ======== hidden layer 1: buf p^1 -> buf p ========
        #pragma unroll
        for (int mt = 0; mt < 8; ++mt) acc[mt] = bias1;
        #pragma unroll
        for (int kt = 0; kt < 4; ++kt) {
            const int kb = (kt * 32 + lk * 8) * 2;
            #pragma unroll
            for (int mh = 0; mh < 2; ++mh) {
                f16x8 bfr[4];
                #pragma unroll
                for (int mi = 0; mi < 4; ++mi)
                    bfr[mi] = *(const f16x8*)(actb[p ^ 1] + actoff((mh * 4 + mi) * 16 + lr, kb));
                #pragma unroll
                for (int mi = 0; mi < 4; ++mi)
                    acc[mh * 4 + mi] = __builtin_amdgcn_mfma_f32_16x16x32_f16(wA1[kt], bfr[mi], acc[mh * 4 + mi], 0, 0, 0);
            }
        }
        #pragma unroll
        for (int mt = 0; mt < 8; ++mt) {
            f16x4 hv;
            #pragma unroll
            for (int i = 0; i < 4; ++i) hv[i] = (f16)sig2(acc[mt][i]);
            *(f16x4*)(actb[p] + actoff(mt * 16 + lr, (C0 + lk * 4) * 2)) = hv;
        }
        __syncthreads();
    }

    // ======== final output for tile TPB-1 (act in buf[(TPB-1)&1] = buf 1) ========
    {
        f32x4 acco = (f32x4){0.f, 0.f, 0.f, 0.f};
        #pragma unroll
        for (int kt = 0; kt < 4; ++kt) {
            f16x8 bfr = *(const f16x8*)(actb[1] + actoff(C0 + lr, (kt * 32 + lk * 8) * 2));
            acco = __builtin_amdgcn_mfma_f32_16x16x32_f16(wOut[kt], bfr, acco, 0, 0, 0);
        }
        if (lk == 0)
            atomicAdd(&out[m_base + (TPB - 1) * BM + C0 + lr], coef * (acco[0] + bout) - f0c);
    }
}

extern "C" void kernel_launch(void* const* d_in, const int* in_sizes, int n_in,
                              void* d_out, int out_size, void* d_ws, size_t ws_size,
                              hipStream_t stream) {
    const float* x   = (const float*)d_in[0];
    const float* f0  = (const float*)d_in[1];
    const float* Wi1 = (const float*)d_in[2];
    const float* bi1 = (const float*)d_in[3];
    const float* Wh1 = (const float*)d_in[4];
    const float* bh1 = (const float*)d_in[5];
    const float* Wo1 = (const float*)d_in[6];
    const float* bo1 = (const float*)d_in[7];
    const float* Wi2 = (const float*)d_in[8];
    const float* bi2 = (const float*)d_in[9];
    const float* Wh2 = (const float*)d_in[10];
    const float* bh2 = (const float*)d_in[11];
    const float* Wo2 = (const float*)d_in[12];
    const float* bo2 = (const float*)d_in[13];
    const float* Wi3 = (const float*)d_in[14];
    const float* bi3 = (const float*)d_in[15];
    const float* Wh3 = (const float*)d_in[16];
    const float* bh3 = (const float*)d_in[17];
    const float* Wo3 = (const float*)d_in[18];
    const float* bo3 = (const float*)d_in[19];
    float* out = (float*)d_out;
    f16* Whf = (f16*)d_ws;                 // ~5.8 MB scaled hidden weights
    f16* WoF = Whf + SW;                   // +23 KB output weights

    hipMemsetAsync(out, 0, (size_t)out_size * sizeof(float), stream);
    hipLaunchKernelGGL(cvt_w, dim3((CVT_TOTAL / 4 + 255) / 256), dim3(256), 0, stream,
                       Wh1, Wh2, Wh3, Wo1, Wo2, Wo3, Whf);
    hipLaunchKernelGGL(hdmr_fused, dim3(NBLK), dim3(NT), 0, stream,
                       x, f0, Wi1, bi1, bh1, bo1,
                       Wi2, bi2, bh2, bo2,
                       Wi3, bi3, bh3, bo3, Whf, WoF, out);
}

// Round 7
// 242.640 us; speedup vs baseline: 1.0554x; 1.0554x over previous
//
#include <hip/hip_runtime.h>

#define HID 128
#define BM 128
#define NT 512
#define TPB 4                 // row-tiles per block
#define GRPS 16               // 8192 / (TPB*BM)
#define NNET 92
#define NBLK (NNET * GRPS)    // 1472, %8==0 -> bijective XCD swizzle
#define LOG2E 1.44269504f

typedef _Float16 f16;
typedef _Float16 f16x2 __attribute__((ext_vector_type(2)));
typedef _Float16 f16x4 __attribute__((ext_vector_type(4)));
typedef _Float16 f16x8 __attribute__((ext_vector_type(8)));
typedef float f32x4 __attribute__((ext_vector_type(4)));

// variable indices per network: 8 singles, 28 pairs, 56 trips (lexicographic)
__constant__ signed char VARS_C[NNET][3] = {
  {0,-1,-1},{1,-1,-1},{2,-1,-1},{3,-1,-1},{4,-1,-1},{5,-1,-1},{6,-1,-1},{7,-1,-1},
  {0,1,-1},{0,2,-1},{0,3,-1},{0,4,-1},{0,5,-1},{0,6,-1},{0,7,-1},
  {1,2,-1},{1,3,-1},{1,4,-1},{1,5,-1},{1,6,-1},{1,7,-1},
  {2,3,-1},{2,4,-1},{2,5,-1},{2,6,-1},{2,7,-1},
  {3,4,-1},{3,5,-1},{3,6,-1},{3,7,-1},
  {4,5,-1},{4,6,-1},{4,7,-1},
  {5,6,-1},{5,7,-1},
  {6,7,-1},
  {0,1,2},{0,1,3},{0,1,4},{0,1,5},{0,1,6},{0,1,7},
  {0,2,3},{0,2,4},{0,2,5},{0,2,6},{0,2,7},
  {0,3,4},{0,3,5},{0,3,6},{0,3,7},
  {0,4,5},{0,4,6},{0,4,7},
  {0,5,6},{0,5,7},
  {0,6,7},
  {1,2,3},{1,2,4},{1,2,5},{1,2,6},{1,2,7},
  {1,3,4},{1,3,5},{1,3,6},{1,3,7},
  {1,4,5},{1,4,6},{1,4,7},
  {1,5,6},{1,5,7},
  {1,6,7},
  {2,3,4},{2,3,5},{2,3,6},{2,3,7},
  {2,4,5},{2,4,6},{2,4,7},
  {2,5,6},{2,5,7},
  {2,6,7},
  {3,4,5},{3,4,6},{3,4,7},
  {3,5,6},{3,5,7},
  {3,6,7},
  {4,5,6},{4,5,7},
  {4,6,7},
  {5,6,7}
};

// final = -35*f0 + sum_n COEF[n] * g_n
__constant__ float COEF_C[NNET] = {
  120.f, 15.f, 15.f, -6.f, -6.f, -6.f, -6.f, -6.f,
  -20.f,-20.f,-20.f,-20.f,-20.f,-20.f,-20.f,-20.f,
  1.f,1.f,1.f,1.f,1.f,1.f,1.f,1.f,1.f,1.f,
  1.f,1.f,1.f,1.f,1.f,1.f,1.f,1.f,1.f,1.f,
  1.f,1.f,1.f,1.f,1.f,1.f,1.f,1.f,1.f,1.f,
  1.f,1.f,1.f,1.f,1.f,1.f,1.f,1.f,1.f,1.f,
  1.f,1.f,1.f,1.f,1.f,1.f,1.f,1.f,1.f,1.f,
  1.f,1.f,1.f,1.f,1.f,1.f,1.f,1.f,1.f,1.f,
  1.f,1.f,1.f,1.f,1.f,1.f,1.f,1.f,1.f,1.f,
  1.f,1.f
};

// s is already -log2e * (pre-activation)  ->  sigmoid = 1/(1+2^s)
__device__ __forceinline__ float sig2(float s) {
    return __builtin_amdgcn_rcpf(1.0f + __builtin_amdgcn_exp2f(s));
}

// XOR-swizzled byte offset into a [row][128] f16 tile (row stride 256 B).
__device__ __forceinline__ int actoff(int row, int colbyte) {
    return row * 256 + (colbyte ^ ((row & 7) << 4));
}

// ---- pre-pass: W_h scaled by -log2e -> f16; W_out -> f16 (unscaled) ----
#define SW 3014656          // 92 * 2*128*128
#define SO1 1024            // 8*128
#define SO2 3584            // 28*128
#define SO3 7168            // 56*128
#define CVT_TOTAL (SW + SO1 + SO2 + SO3)
__global__ __launch_bounds__(256)
void cvt_w(const float* __restrict__ Wh1, const float* __restrict__ Wh2,
           const float* __restrict__ Wh3, const float* __restrict__ Wo1,
           const float* __restrict__ Wo2, const float* __restrict__ Wo3,
           f16* __restrict__ dst) {
    const int i = (blockIdx.x * 256 + threadIdx.x) * 4;
    if (i >= CVT_TOTAL) return;
    float scale;
    const float* s;
    if (i < SW) {           // hidden weights, scaled (group sizes all %4==0)
        scale = -LOG2E;
        if (i < 262144)         s = Wh1 + i;
        else if (i < 1179648)   s = Wh2 + (i - 262144);
        else                    s = Wh3 + (i - 1179648);
    } else {                // output weights, unscaled
        scale = 1.0f;
        int j = i - SW;
        if (j < SO1)            s = Wo1 + j;
        else if (j < SO1 + SO2) s = Wo2 + (j - SO1);
        else                    s = Wo3 + (j - SO1 - SO2);
    }
    float4 v = *(const float4*)s;
    f16x4 h = { (f16)(scale*v.x), (f16)(scale*v.y), (f16)(scale*v.z), (f16)(scale*v.w) };
    *(f16x4*)(dst + i) = h;
}

__global__ __launch_bounds__(NT, 4)   // <=128 VGPR -> 2 blocks/CU (LDS-bound)
void hdmr_fused(const float* __restrict__ x, const float* __restrict__ f0p,
    const float* __restrict__ Wi1, const float* __restrict__ bi1,
    const float* __restrict__ bh1, const float* __restrict__ bo1,
    const float* __restrict__ Wi2, const float* __restrict__ bi2,
    const float* __restrict__ bh2, const float* __restrict__ bo2,
    const float* __restrict__ Wi3, const float* __restrict__ bi3,
    const float* __restrict__ bh3, const float* __restrict__ bo3,
    const f16* __restrict__ Whf, const f16* __restrict__ WoF,
    float* __restrict__ out)
{
    __shared__ __attribute__((aligned(16))) char actb[2][BM * HID * 2]; // 64KB ping-pong
    __shared__ __attribute__((aligned(16))) float xr[2][BM * 8];        // 8KB raw x tiles
    __shared__ float wi_s[HID][3];
    __shared__ float bi_s[HID];

    const int tid = threadIdx.x;
    const int bid = blockIdx.x;
    const int swz = (bid & 7) * (NBLK / 8) + (bid >> 3);   // bijective XCD swizzle
    const int N = swz >> 4;            // network id 0..91
    const int grp = swz & (GRPS - 1);
    const int m_base = grp * (TPB * BM);

    int din, lidx;
    const float *Wi, *bi, *bh, *bo;
    if (N < 8)       { lidx = N;      din = 1; Wi=Wi1; bi=bi1; bh=bh1; bo=bo1; }
    else if (N < 36) { lidx = N - 8;  din = 2; Wi=Wi2; bi=bi2; bh=bh2; bo=bo2; }
    else             { lidx = N - 36; din = 3; Wi=Wi3; bi=bi3; bh=bh3; bo=bo3; }
    Wi += (size_t)lidx * HID * din;
    bi += (size_t)lidx * HID;
    bh += (size_t)lidx * 2 * HID;
    const float bout = bo[lidx];
    const float coef = COEF_C[N];
    const float f0c = (N == 0) ? 35.0f * f0p[0] : 0.0f;
    const f16* WN = Whf + (size_t)N * (2 * HID * HID);

    const int lane = tid & 63;
    const int wv = tid >> 6;           // 8 waves
    const int lr = lane & 15;
    const int lk = lane >> 4;          // 0..3
    const int C0 = wv * 16;            // this wave's 16-col (j) slice; also its 16-row band

    // ---- permanent register state: hidden/output weight fragments ----
    f16x8 wA0[4], wA1[4], wOut[4];
    #pragma unroll
    for (int kt = 0; kt < 4; ++kt) {
        wA0[kt] = *(const f16x8*)(WN + (size_t)(C0 + lr) * HID + kt * 32 + lk * 8);
        wA1[kt] = *(const f16x8*)(WN + HID * HID + (size_t)(C0 + lr) * HID + kt * 32 + lk * 8);
        wOut[kt] = *(const f16x8*)(WoF + (size_t)N * HID + kt * 32 + lk * 8);
    }
    f32x4 bias0 = *(const f32x4*)(bh + C0 + lk * 4);
    f32x4 bias1 = *(const f32x4*)(bh + HID + C0 + lk * 4);
    #pragma unroll
    for (int i = 0; i < 4; ++i) { bias0[i] *= -LOG2E; bias1[i] *= -LOG2E; }

    const int v0 = VARS_C[N][0];
    const int v1 = VARS_C[N][1] < 0 ? 0 : VARS_C[N][1];
    const int v2 = VARS_C[N][2] < 0 ? 0 : VARS_C[N][2];

    // ---- stage input-layer weights (scaled, zero-padded) + first x tile ----
    if (tid < HID) {
        #pragma unroll
        for (int ii = 0; ii < 3; ++ii)
            wi_s[tid][ii] = (ii < din) ? -LOG2E * Wi[tid * din + ii] : 0.0f;
        bi_s[tid] = -LOG2E * bi[tid];
    }
    if (tid < 256)
        ((float4*)xr[0])[tid] = ((const float4*)(x + (size_t)m_base * 8))[tid];
    __syncthreads();

    f32x4 acc[8];

    for (int t = 0; t < TPB; ++t) {
        const int p = t & 1;
        // ======== phase A: output MFMA for tile t-1 (buf p^1) + input layer t (buf p) ========
        f32x4 acco = (f32x4){0.f, 0.f, 0.f, 0.f};
        if (t > 0) {
            #pragma unroll
            for (int kt = 0; kt < 4; ++kt) {
                f16x8 bfr = *(const f16x8*)(actb[p ^ 1] + actoff(C0 + lr, (kt * 32 + lk * 8) * 2));
                acco = __builtin_amdgcn_mfma_f32_16x16x32_f16(wOut[kt], bfr, acco, 0, 0, 0);
            }
        }
        {   // input layer: band rows (uniform across lanes), lane covers cols lane*2..+1
            // -> LDS write is contiguous 256B (XOR-permuted, 2 lanes/bank = free);
            // weights come from LDS (short live ranges, rematerializable)
            const int cA = lane * 2;
            const float wAc0 = wi_s[cA][0],     wAc1 = wi_s[cA][1],     wAc2 = wi_s[cA][2];
            const float wBc0 = wi_s[cA + 1][0], wBc1 = wi_s[cA + 1][1], wBc2 = wi_s[cA + 1][2];
            const float bAc = bi_s[cA], bBc = bi_s[cA + 1];
            #pragma unroll
            for (int rr = 0; rr < 16; ++rr) {
                const int row = C0 + rr;
                const float* xrow = &xr[p][row * 8];      // uniform addr -> broadcast
                const float x0 = xrow[v0], x1 = xrow[v1], x2 = xrow[v2];
                float sA = bAc + x0 * wAc0 + x1 * wAc1 + x2 * wAc2;
                float sB = bBc + x0 * wBc0 + x1 * wBc1 + x2 * wBc2;
                f16x2 hv = { (f16)sig2(sA), (f16)sig2(sB) };
                *(f16x2*)(actb[p] + actoff(row, lane * 4)) = hv;
            }
        }
        if (t > 0 && lk == 0) {
            // D[j][m]: wout replicated over j -> every lane holds out[m=lr]; lanes lk==0 commit
            atomicAdd(&out[m_base + (t - 1) * BM + C0 + lr], coef * (acco[0] + bout) - f0c);
        }
        __syncthreads();

        // ======== hidden layer 0: buf p -> buf p^1 ========
        #pragma unroll
        for (int mt = 0; mt < 8; ++mt) acc[mt] = bias0;
        #pragma unroll
        for (int kt = 0; kt < 4; ++kt) {
            const int kb = (kt * 32 + lk * 8) * 2;
            #pragma unroll
            for (int mh = 0; mh < 2; ++mh) {   // halves to limit live bfr regs
                f16x8 bfr[4];
                #pragma unroll
                for (int mi = 0; mi < 4; ++mi)
                    bfr[mi] = *(const f16x8*)(actb[p] + actoff((mh * 4 + mi) * 16 + lr, kb));
                #pragma unroll
                for (int mi = 0; mi < 4; ++mi)
                    acc[mh * 4 + mi] = __builtin_amdgcn_mfma_f32_16x16x32_f16(wA0[kt], bfr[mi], acc[mh * 4 + mi], 0, 0, 0);
            }
        }
        // prefetch next x tile (waves 0-3) while MFMAs drain
        if (t + 1 < TPB && tid < 256)
            ((float4*)xr[p ^ 1])[tid] = ((const float4*)(x + (size_t)(m_base + (t + 1) * BM) * 8))[tid];
        #pragma unroll
        for (int mt = 0; mt < 8; ++mt) {
            f16x4 hv;
            #pragma unroll
            for (int i = 0; i < 4; ++i) hv[i] = (f16)sig2(acc[mt][i]);
            *(f16x4*)(actb[p ^ 1] + actoff(mt * 16 + lr, (C0 + lk * 4) * 2)) = hv;
        }
        __syncthreads();

        // ======== hidden layer 1: buf p^1 -> buf p ========
        #pragma unroll
        for (int mt = 0; mt < 8; ++mt) acc[mt] = bias1;
        #pragma unroll
        for (int kt = 0; kt < 4; ++kt) {
            const int kb = (kt * 32 + lk * 8) * 2;
            #pragma unroll
            for (int mh = 0; mh < 2; ++mh) {
                f16x8 bfr[4];
                #pragma unroll
                for (int mi = 0; mi < 4; ++mi)
                    bfr[mi] = *(const f16x8*)(actb[p ^ 1] + actoff((mh * 4 + mi) * 16 + lr, kb));
                #pragma unroll
                for (int mi = 0; mi < 4; ++mi)
                    acc[mh * 4 + mi] = __builtin_amdgcn_mfma_f32_16x16x32_f16(wA1[kt], bfr[mi], acc[mh * 4 + mi], 0, 0, 0);
            }
        }
        #pragma unroll
        for (int mt = 0; mt < 8; ++mt) {
            f16x4 hv;
            #pragma unroll
            for (int i = 0; i < 4; ++i) hv[i] = (f16)sig2(acc[mt][i]);
            *(f16x4*)(actb[p] + actoff(mt * 16 + lr, (C0 + lk * 4) * 2)) = hv;
        }
        __syncthreads();
    }

    // ======== final output for tile TPB-1 (act in buf[(TPB-1)&1] = buf 1) ========
    {
        f32x4 acco = (f32x4){0.f, 0.f, 0.f, 0.f};
        #pragma unroll
        for (int kt = 0; kt < 4; ++kt) {
            f16x8 bfr = *(const f16x8*)(actb[1] + actoff(C0 + lr, (kt * 32 + lk * 8) * 2));
            acco = __builtin_amdgcn_mfma_f32_16x16x32_f16(wOut[kt], bfr, acco, 0, 0, 0);
        }
        if (lk == 0)
            atomicAdd(&out[m_base + (TPB - 1) * BM + C0 + lr], coef * (acco[0] + bout) - f0c);
    }
}

extern "C" void kernel_launch(void* const* d_in, const int* in_sizes, int n_in,
                              void* d_out, int out_size, void* d_ws, size_t ws_size,
                              hipStream_t stream) {
    const float* x   = (const float*)d_in[0];
    const float* f0  = (const float*)d_in[1];
    const float* Wi1 = (const float*)d_in[2];
    const float* bi1 = (const float*)d_in[3];
    const float* Wh1 = (const float*)d_in[4];
    const float* bh1 = (const float*)d_in[5];
    const float* Wo1 = (const float*)d_in[6];
    const float* bo1 = (const float*)d_in[7];
    const float* Wi2 = (const float*)d_in[8];
    const float* bi2 = (const float*)d_in[9];
    const float* Wh2 = (const float*)d_in[10];
    const float* bh2 = (const float*)d_in[11];
    const float* Wo2 = (const float*)d_in[12];
    const float* bo2 = (const float*)d_in[13];
    const float* Wi3 = (const float*)d_in[14];
    const float* bi3 = (const float*)d_in[15];
    const float* Wh3 = (const float*)d_in[16];
    const float* bh3 = (const float*)d_in[17];
    const float* Wo3 = (const float*)d_in[18];
    const float* bo3 = (const float*)d_in[19];
    float* out = (float*)d_out;
    f16* Whf = (f16*)d_ws;                 // ~5.8 MB scaled hidden weights
    f16* WoF = Whf + SW;                   // +23 KB output weights

    hipMemsetAsync(out, 0, (size_t)out_size * sizeof(float), stream);
    hipLaunchKernelGGL(cvt_w, dim3((CVT_TOTAL / 4 + 255) / 256), dim3(256), 0, stream,
                       Wh1, Wh2, Wh3, Wo1, Wo2, Wo3, Whf);
    hipLaunchKernelGGL(hdmr_fused, dim3(NBLK), dim3(NT), 0, stream,
                       x, f0, Wi1, bi1, bh1, bo1,
                       Wi2, bi2, bh2, bo2,
                       Wi3, bi3, bh3, bo3, Whf, WoF, out);
}

// Round 8
// 230.516 us; speedup vs baseline: 1.1110x; 1.0526x over previous
//
#include <hip/hip_runtime.h>

#define HID 128
#define BM 128
#define NT 512
#define TPB 4                 // row-tiles per block
#define GRPS 16               // 8192 / (TPB*BM)
#define NNET 92
#define NBLK (NNET * GRPS)    // 1472, %8==0 -> bijective XCD swizzle
#define LOG2E 1.44269504f
#define NROWS 8192

typedef _Float16 f16;
typedef _Float16 f16x2 __attribute__((ext_vector_type(2)));
typedef _Float16 f16x4 __attribute__((ext_vector_type(4)));
typedef _Float16 f16x8 __attribute__((ext_vector_type(8)));
typedef float f32x4 __attribute__((ext_vector_type(4)));

// variable indices per network: 8 singles, 28 pairs, 56 trips (lexicographic)
__constant__ signed char VARS_C[NNET][3] = {
  {0,-1,-1},{1,-1,-1},{2,-1,-1},{3,-1,-1},{4,-1,-1},{5,-1,-1},{6,-1,-1},{7,-1,-1},
  {0,1,-1},{0,2,-1},{0,3,-1},{0,4,-1},{0,5,-1},{0,6,-1},{0,7,-1},
  {1,2,-1},{1,3,-1},{1,4,-1},{1,5,-1},{1,6,-1},{1,7,-1},
  {2,3,-1},{2,4,-1},{2,5,-1},{2,6,-1},{2,7,-1},
  {3,4,-1},{3,5,-1},{3,6,-1},{3,7,-1},
  {4,5,-1},{4,6,-1},{4,7,-1},
  {5,6,-1},{5,7,-1},
  {6,7,-1},
  {0,1,2},{0,1,3},{0,1,4},{0,1,5},{0,1,6},{0,1,7},
  {0,2,3},{0,2,4},{0,2,5},{0,2,6},{0,2,7},
  {0,3,4},{0,3,5},{0,3,6},{0,3,7},
  {0,4,5},{0,4,6},{0,4,7},
  {0,5,6},{0,5,7},
  {0,6,7},
  {1,2,3},{1,2,4},{1,2,5},{1,2,6},{1,2,7},
  {1,3,4},{1,3,5},{1,3,6},{1,3,7},
  {1,4,5},{1,4,6},{1,4,7},
  {1,5,6},{1,5,7},
  {1,6,7},
  {2,3,4},{2,3,5},{2,3,6},{2,3,7},
  {2,4,5},{2,4,6},{2,4,7},
  {2,5,6},{2,5,7},
  {2,6,7},
  {3,4,5},{3,4,6},{3,4,7},
  {3,5,6},{3,5,7},
  {3,6,7},
  {4,5,6},{4,5,7},
  {4,6,7},
  {5,6,7}
};

// final = -35*f0 + sum_n COEF[n] * g_n
__constant__ float COEF_C[NNET] = {
  120.f, 15.f, 15.f, -6.f, -6.f, -6.f, -6.f, -6.f,
  -20.f,-20.f,-20.f,-20.f,-20.f,-20.f,-20.f,-20.f,
  1.f,1.f,1.f,1.f,1.f,1.f,1.f,1.f,1.f,1.f,
  1.f,1.f,1.f,1.f,1.f,1.f,1.f,1.f,1.f,1.f,
  1.f,1.f,1.f,1.f,1.f,1.f,1.f,1.f,1.f,1.f,
  1.f,1.f,1.f,1.f,1.f,1.f,1.f,1.f,1.f,1.f,
  1.f,1.f,1.f,1.f,1.f,1.f,1.f,1.f,1.f,1.f,
  1.f,1.f,1.f,1.f,1.f,1.f,1.f,1.f,1.f,1.f,
  1.f,1.f,1.f,1.f,1.f,1.f,1.f,1.f,1.f,1.f,
  1.f,1.f
};

// s is already -log2e * (pre-activation)  ->  sigmoid = 1/(1+2^s)
__device__ __forceinline__ float sig2(float s) {
    return __builtin_amdgcn_rcpf(1.0f + __builtin_amdgcn_exp2f(s));
}

// XOR-swizzled byte offset into a [row][128] f16 tile (row stride 256 B).
__device__ __forceinline__ int actoff(int row, int colbyte) {
    return row * 256 + (colbyte ^ ((row & 7) << 4));
}

// ---- pre-pass: W_h scaled by -log2e -> f16; W_out -> f16 (unscaled) ----
#define SW 3014656          // 92 * 2*128*128
#define SO1 1024            // 8*128
#define SO2 3584            // 28*128
#define SO3 7168            // 56*128
#define CVT_TOTAL (SW + SO1 + SO2 + SO3)
__global__ __launch_bounds__(256)
void cvt_w(const float* __restrict__ Wh1, const float* __restrict__ Wh2,
           const float* __restrict__ Wh3, const float* __restrict__ Wo1,
           const float* __restrict__ Wo2, const float* __restrict__ Wo3,
           f16* __restrict__ dst) {
    const int i = (blockIdx.x * 256 + threadIdx.x) * 4;
    if (i >= CVT_TOTAL) return;
    float scale;
    const float* s;
    if (i < SW) {           // hidden weights, scaled (group sizes all %4==0)
        scale = -LOG2E;
        if (i < 262144)         s = Wh1 + i;
        else if (i < 1179648)   s = Wh2 + (i - 262144);
        else                    s = Wh3 + (i - 1179648);
    } else {                // output weights, unscaled
        scale = 1.0f;
        int j = i - SW;
        if (j < SO1)            s = Wo1 + j;
        else if (j < SO1 + SO2) s = Wo2 + (j - SO1);
        else                    s = Wo3 + (j - SO1 - SO2);
    }
    float4 v = *(const float4*)s;
    f16x4 h = { (f16)(scale*v.x), (f16)(scale*v.y), (f16)(scale*v.z), (f16)(scale*v.w) };
    *(f16x4*)(dst + i) = h;
}

// ---- final reduction: out[r] = sum_n part[n][r] (f0/bias/coef already folded) ----
__global__ __launch_bounds__(128)
void reduce_out(const float* __restrict__ part, float* __restrict__ out) {
    const int r4 = blockIdx.x * 128 + threadIdx.x;   // float4 index, 2048 total
    const float4* p4 = (const float4*)part;
    float4 s = p4[r4];
    #pragma unroll 4
    for (int n = 1; n < NNET; ++n) {
        float4 v = p4[(size_t)n * (NROWS / 4) + r4];
        s.x += v.x; s.y += v.y; s.z += v.z; s.w += v.w;
    }
    ((float4*)out)[r4] = s;
}

__global__ __launch_bounds__(NT, 4)   // <=128 VGPR -> 2 blocks/CU (LDS-bound)
void hdmr_fused(const float* __restrict__ x, const float* __restrict__ f0p,
    const float* __restrict__ Wi1, const float* __restrict__ bi1,
    const float* __restrict__ bh1, const float* __restrict__ bo1,
    const float* __restrict__ Wi2, const float* __restrict__ bi2,
    const float* __restrict__ bh2, const float* __restrict__ bo2,
    const float* __restrict__ Wi3, const float* __restrict__ bi3,
    const float* __restrict__ bh3, const float* __restrict__ bo3,
    const f16* __restrict__ Whf, const f16* __restrict__ WoF,
    float* __restrict__ part)
{
    __shared__ __attribute__((aligned(16))) char actb[2][BM * HID * 2]; // 64KB ping-pong
    __shared__ __attribute__((aligned(16))) float xr[2][BM * 8];        // 8KB raw x tiles
    __shared__ float wi_s[HID][3];
    __shared__ float bi_s[HID];

    const int tid = threadIdx.x;
    const int bid = blockIdx.x;
    const int swz = (bid & 7) * (NBLK / 8) + (bid >> 3);   // bijective XCD swizzle
    const int N = swz >> 4;            // network id 0..91
    const int grp = swz & (GRPS - 1);
    const int m_base = grp * (TPB * BM);

    int din, lidx;
    const float *Wi, *bi, *bh, *bo;
    if (N < 8)       { lidx = N;      din = 1; Wi=Wi1; bi=bi1; bh=bh1; bo=bo1; }
    else if (N < 36) { lidx = N - 8;  din = 2; Wi=Wi2; bi=bi2; bh=bh2; bo=bo2; }
    else             { lidx = N - 36; din = 3; Wi=Wi3; bi=bi3; bh=bh3; bo=bo3; }
    Wi += (size_t)lidx * HID * din;
    bi += (size_t)lidx * HID;
    bh += (size_t)lidx * 2 * HID;
    const float bout = bo[lidx];
    const float coef = COEF_C[N];
    const float f0c = (N == 0) ? 35.0f * f0p[0] : 0.0f;
    const f16* WN = Whf + (size_t)N * (2 * HID * HID);
    float* partN = part + (size_t)N * NROWS + m_base;

    const int lane = tid & 63;
    const int wv = tid >> 6;           // 8 waves
    const int lr = lane & 15;
    const int lk = lane >> 4;          // 0..3
    const int C0 = wv * 16;            // this wave's 16-col (j) slice; also its 16-row band

    // ---- permanent register state: hidden/output weight fragments ----
    f16x8 wA0[4], wA1[4], wOut[4];
    #pragma unroll
    for (int kt = 0; kt < 4; ++kt) {
        wA0[kt] = *(const f16x8*)(WN + (size_t)(C0 + lr) * HID + kt * 32 + lk * 8);
        wA1[kt] = *(const f16x8*)(WN + HID * HID + (size_t)(C0 + lr) * HID + kt * 32 + lk * 8);
        wOut[kt] = *(const f16x8*)(WoF + (size_t)N * HID + kt * 32 + lk * 8);
    }
    f32x4 bias0 = *(const f32x4*)(bh + C0 + lk * 4);
    f32x4 bias1 = *(const f32x4*)(bh + HID + C0 + lk * 4);
    #pragma unroll
    for (int i = 0; i < 4; ++i) { bias0[i] *= -LOG2E; bias1[i] *= -LOG2E; }

    const int v0 = VARS_C[N][0];
    const int v1 = VARS_C[N][1] < 0 ? 0 : VARS_C[N][1];
    const int v2 = VARS_C[N][2] < 0 ? 0 : VARS_C[N][2];

    // ---- stage input-layer weights (scaled, zero-padded) + first x tile ----
    if (tid < HID) {
        #pragma unroll
        for (int ii = 0; ii < 3; ++ii)
            wi_s[tid][ii] = (ii < din) ? -LOG2E * Wi[tid * din + ii] : 0.0f;
        bi_s[tid] = -LOG2E * bi[tid];
    }
    if (tid < 256)
        ((float4*)xr[0])[tid] = ((const float4*)(x + (size_t)m_base * 8))[tid];
    __syncthreads();

    f32x4 acc[8];

    for (int t = 0; t < TPB; ++t) {
        const int p = t & 1;
        // ======== phase A: output MFMA for tile t-1 (buf p^1) + input layer t (buf p) ========
        f32x4 acco = (f32x4){0.f, 0.f, 0.f, 0.f};
        if (t > 0) {
            #pragma unroll
            for (int kt = 0; kt < 4; ++kt) {
                f16x8 bfr = *(const f16x8*)(actb[p ^ 1] + actoff(C0 + lr, (kt * 32 + lk * 8) * 2));
                acco = __builtin_amdgcn_mfma_f32_16x16x32_f16(wOut[kt], bfr, acco, 0, 0, 0);
            }
        }
        {   // input layer: this wave's 16-row band, lane covers row C0+lr, cols lk*32..+32.
            // Results accumulate in 4 f16x8 regs (phase-local), then 4 ds_write_b128:
            // bank pattern 16(lk0^lr2)+4(qq^lr[1:0]) covers all 32 banks uniformly -> conflict-free
            const int r = C0 + lr;
            const float* xrow = &xr[p][r * 8];
            const float x0 = xrow[v0], x1 = xrow[v1], x2 = xrow[v2];
            f16x8 pk[4];
            #pragma unroll
            for (int q = 0; q < 16; ++q) {
                const int c = lk * 32 + q * 2;
                float sA = bi_s[c]     + x0 * wi_s[c][0]     + x1 * wi_s[c][1]     + x2 * wi_s[c][2];
                float sB = bi_s[c + 1] + x0 * wi_s[c + 1][0] + x1 * wi_s[c + 1][1] + x2 * wi_s[c + 1][2];
                pk[q >> 2][(q & 3) * 2]     = (f16)sig2(sA);
                pk[q >> 2][(q & 3) * 2 + 1] = (f16)sig2(sB);
            }
            #pragma unroll
            for (int qq = 0; qq < 4; ++qq)
                *(f16x8*)(actb[p] + actoff(r, (lk * 32 + qq * 8) * 2)) = pk[qq];
        }
        if (t > 0 && lk == 0) {
            // D[j][m]: wout replicated over j -> every lane holds out[m=lr]; lanes lk==0 commit.
            // Private per-(net,row) slot: no atomics, no cross-XCD line sharing.
            partN[(t - 1) * BM + C0 + lr] = coef * (acco[0] + bout) - f0c;
        }
        __syncthreads();

        // ======== hidden layer 0: buf p -> buf p^1 ========
        #pragma unroll
        for (int mt = 0; mt < 8; ++mt) acc[mt] = bias0;
        #pragma unroll
        for (int kt = 0; kt < 4; ++kt) {
            const int kb = (kt * 32 + lk * 8) * 2;
            #pragma unroll
            for (int mh = 0; mh < 2; ++mh) {   // halves to limit live bfr regs
                f16x8 bfr[4];
                #pragma unroll
                for (int mi = 0; mi < 4; ++mi)
                    bfr[mi] = *(const f16x8*)(actb[p] + actoff((mh * 4 + mi) * 16 + lr, kb));
                #pragma unroll
                for (int mi = 0; mi < 4; ++mi)
                    acc[mh * 4 + mi] = __builtin_amdgcn_mfma_f32_16x16x32_f16(wA0[kt], bfr[mi], acc[mh * 4 + mi], 0, 0, 0);
            }
        }
        // prefetch next x tile (waves 0-3) while MFMAs drain
        if (t + 1 < TPB && tid < 256)
            ((float4*)xr[p ^ 1])[tid] = ((const float4*)(x + (size_t)(m_base + (t + 1) * BM) * 8))[tid];
        #pragma unroll
        for (int mt = 0; mt < 8; ++mt) {
            f16x4 hv;
            #pragma unroll
            for (int i = 0; i < 4; ++i) hv[i] = (f16)sig2(acc[mt][i]);
            *(f16x4*)(actb[p ^ 1] + actoff(mt * 16 + lr, (C0 + lk * 4) * 2)) = hv;
        }
        __syncthreads();

        // ======== hidden layer 1: buf p^1 -> buf p ========
        #pragma unroll
        for (int mt = 0; mt < 8; ++mt) acc[mt] = bias1;
        #pragma unroll
        for (int kt = 0; kt < 4; ++kt) {
            const int kb = (kt * 32 + lk * 8) * 2;
            #pragma unroll
            for (int mh = 0; mh < 2; ++mh) {
                f16x8 bfr[4];
                #pragma unroll
                for (int mi = 0; mi < 4; ++mi)
                    bfr[mi] = *(const f16x8*)(actb[p ^ 1] + actoff((mh * 4 + mi) * 16 + lr, kb));
                #pragma unroll
                for (int mi = 0; mi < 4; ++mi)
                    acc[mh * 4 + mi] = __builtin_amdgcn_mfma_f32_16x16x32_f16(wA1[kt], bfr[mi], acc[mh * 4 + mi], 0, 0, 0);
            }
        }
        #pragma unroll
        for (int mt = 0; mt < 8; ++mt) {
            f16x4 hv;
            #pragma unroll
            for (int i = 0; i < 4; ++i) hv[i] = (f16)sig2(acc[mt][i]);
            *(f16x4*)(actb[p] + actoff(mt * 16 + lr, (C0 + lk * 4) * 2)) = hv;
        }
        __syncthreads();
    }

    // ======== final output for tile TPB-1 (act in buf[(TPB-1)&1] = buf 1) ========
    {
        f32x4 acco = (f32x4){0.f, 0.f, 0.f, 0.f};
        #pragma unroll
        for (int kt = 0; kt < 4; ++kt) {
            f16x8 bfr = *(const f16x8*)(actb[1] + actoff(C0 + lr, (kt * 32 + lk * 8) * 2));
            acco = __builtin_amdgcn_mfma_f32_16x16x32_f16(wOut[kt], bfr, acco, 0, 0, 0);
        }
        if (lk == 0)
            partN[(TPB - 1) * BM + C0 + lr] = coef * (acco[0] + bout) - f0c;
    }
}

extern "C" void kernel_launch(void* const* d_in, const int* in_sizes, int n_in,
                              void* d_out, int out_size, void* d_ws, size_t ws_size,
                              hipStream_t stream) {
    const float* x   = (const float*)d_in[0];
    const float* f0  = (const float*)d_in[1];
    const float* Wi1 = (const float*)d_in[2];
    const float* bi1 = (const float*)d_in[3];
    const float* Wh1 = (const float*)d_in[4];
    const float* bh1 = (const float*)d_in[5];
    const float* Wo1 = (const float*)d_in[6];
    const float* bo1 = (const float*)d_in[7];
    const float* Wi2 = (const float*)d_in[8];
    const float* bi2 = (const float*)d_in[9];
    const float* Wh2 = (const float*)d_in[10];
    const float* bh2 = (const float*)d_in[11];
    const float* Wo2 = (const float*)d_in[12];
    const float* bo2 = (const float*)d_in[13];
    const float* Wi3 = (const float*)d_in[14];
    const float* bi3 = (const float*)d_in[15];
    const float* Wh3 = (const float*)d_in[16];
    const float* bh3 = (const float*)d_in[17];
    const float* Wo3 = (const float*)d_in[18];
    const float* bo3 = (const float*)d_in[19];
    float* out = (float*)d_out;

    f16* Whf = (f16*)d_ws;                       // ~5.8 MB scaled hidden weights
    f16* WoF = Whf + SW;                         // +23 KB output weights
    float* part = (float*)(Whf + SW + 16384);    // 92*8192*4B = 3 MB partials (16KB pad keeps alignment)

    hipLaunchKernelGGL(cvt_w, dim3((CVT_TOTAL / 4 + 255) / 256), dim3(256), 0, stream,
                       Wh1, Wh2, Wh3, Wo1, Wo2, Wo3, Whf);
    hipLaunchKernelGGL(hdmr_fused, dim3(NBLK), dim3(NT), 0, stream,
                       x, f0, Wi1, bi1, bh1, bo1,
                       Wi2, bi2, bh2, bo2,
                       Wi3, bi3, bh3, bo3, Whf, WoF, part);
    hipLaunchKernelGGL(reduce_out, dim3(NROWS / 4 / 128), dim3(128), 0, stream,
                       part, out);
}

// Round 9
// 230.445 us; speedup vs baseline: 1.1113x; 1.0003x over previous
//
#include <hip/hip_runtime.h>

#define HID 128
#define BM 128
#define NT 512
#define TPB 4                 // row-tiles per block
#define GRPS 16               // 8192 / (TPB*BM)
#define NNET 92
#define NBLK (NNET * GRPS)    // 1472, %8==0 -> bijective XCD swizzle
#define LOG2E 1.44269504f
#define NROWS 8192

typedef _Float16 f16;
typedef _Float16 f16x2 __attribute__((ext_vector_type(2)));
typedef _Float16 f16x4 __attribute__((ext_vector_type(4)));
typedef _Float16 f16x8 __attribute__((ext_vector_type(8)));
typedef float f32x4 __attribute__((ext_vector_type(4)));

// variable indices per network: 8 singles, 28 pairs, 56 trips (lexicographic)
__constant__ signed char VARS_C[NNET][3] = {
  {0,-1,-1},{1,-1,-1},{2,-1,-1},{3,-1,-1},{4,-1,-1},{5,-1,-1},{6,-1,-1},{7,-1,-1},
  {0,1,-1},{0,2,-1},{0,3,-1},{0,4,-1},{0,5,-1},{0,6,-1},{0,7,-1},
  {1,2,-1},{1,3,-1},{1,4,-1},{1,5,-1},{1,6,-1},{1,7,-1},
  {2,3,-1},{2,4,-1},{2,5,-1},{2,6,-1},{2,7,-1},
  {3,4,-1},{3,5,-1},{3,6,-1},{3,7,-1},
  {4,5,-1},{4,6,-1},{4,7,-1},
  {5,6,-1},{5,7,-1},
  {6,7,-1},
  {0,1,2},{0,1,3},{0,1,4},{0,1,5},{0,1,6},{0,1,7},
  {0,2,3},{0,2,4},{0,2,5},{0,2,6},{0,2,7},
  {0,3,4},{0,3,5},{0,3,6},{0,3,7},
  {0,4,5},{0,4,6},{0,4,7},
  {0,5,6},{0,5,7},
  {0,6,7},
  {1,2,3},{1,2,4},{1,2,5},{1,2,6},{1,2,7},
  {1,3,4},{1,3,5},{1,3,6},{1,3,7},
  {1,4,5},{1,4,6},{1,4,7},
  {1,5,6},{1,5,7},
  {1,6,7},
  {2,3,4},{2,3,5},{2,3,6},{2,3,7},
  {2,4,5},{2,4,6},{2,4,7},
  {2,5,6},{2,5,7},
  {2,6,7},
  {3,4,5},{3,4,6},{3,4,7},
  {3,5,6},{3,5,7},
  {3,6,7},
  {4,5,6},{4,5,7},
  {4,6,7},
  {5,6,7}
};

// final = -35*f0 + sum_n COEF[n] * g_n
__constant__ float COEF_C[NNET] = {
  120.f, 15.f, 15.f, -6.f, -6.f, -6.f, -6.f, -6.f,
  -20.f,-20.f,-20.f,-20.f,-20.f,-20.f,-20.f,-20.f,
  1.f,1.f,1.f,1.f,1.f,1.f,1.f,1.f,1.f,1.f,
  1.f,1.f,1.f,1.f,1.f,1.f,1.f,1.f,1.f,1.f,
  1.f,1.f,1.f,1.f,1.f,1.f,1.f,1.f,1.f,1.f,
  1.f,1.f,1.f,1.f,1.f,1.f,1.f,1.f,1.f,1.f,
  1.f,1.f,1.f,1.f,1.f,1.f,1.f,1.f,1.f,1.f,
  1.f,1.f,1.f,1.f,1.f,1.f,1.f,1.f,1.f,1.f,
  1.f,1.f,1.f,1.f,1.f,1.f,1.f,1.f,1.f,1.f,
  1.f,1.f
};

// s is already -log2e * (pre-activation)  ->  sigmoid = 1/(1+2^s)
__device__ __forceinline__ float sig2(float s) {
    return __builtin_amdgcn_rcpf(1.0f + __builtin_amdgcn_exp2f(s));
}

// XOR-swizzled byte offset into a [row][128] f16 tile (row stride 256 B).
__device__ __forceinline__ int actoff(int row, int colbyte) {
    return row * 256 + (colbyte ^ ((row & 7) << 4));
}

// ---- pre-pass: W_h scaled by -log2e -> f16; W_out -> f16 (unscaled) ----
#define SW 3014656          // 92 * 2*128*128
#define SO1 1024            // 8*128
#define SO2 3584            // 28*128
#define SO3 7168            // 56*128
#define CVT_TOTAL (SW + SO1 + SO2 + SO3)
__global__ __launch_bounds__(256)
void cvt_w(const float* __restrict__ Wh1, const float* __restrict__ Wh2,
           const float* __restrict__ Wh3, const float* __restrict__ Wo1,
           const float* __restrict__ Wo2, const float* __restrict__ Wo3,
           f16* __restrict__ dst) {
    const int i = (blockIdx.x * 256 + threadIdx.x) * 4;
    if (i >= CVT_TOTAL) return;
    float scale;
    const float* s;
    if (i < SW) {           // hidden weights, scaled (group sizes all %4==0)
        scale = -LOG2E;
        if (i < 262144)         s = Wh1 + i;
        else if (i < 1179648)   s = Wh2 + (i - 262144);
        else                    s = Wh3 + (i - 1179648);
    } else {                // output weights, unscaled
        scale = 1.0f;
        int j = i - SW;
        if (j < SO1)            s = Wo1 + j;
        else if (j < SO1 + SO2) s = Wo2 + (j - SO1);
        else                    s = Wo3 + (j - SO1 - SO2);
    }
    float4 v = *(const float4*)s;
    f16x4 h = { (f16)(scale*v.x), (f16)(scale*v.y), (f16)(scale*v.z), (f16)(scale*v.w) };
    *(f16x4*)(dst + i) = h;
}

// ---- final reduction: out[r] = sum_n part[n][r] (f0/bias/coef already folded) ----
__global__ __launch_bounds__(128)
void reduce_out(const float* __restrict__ part, float* __restrict__ out) {
    const int r4 = blockIdx.x * 128 + threadIdx.x;   // float4 index, 2048 total
    const float4* p4 = (const float4*)part;
    float4 s = p4[r4];
    #pragma unroll 4
    for (int n = 1; n < NNET; ++n) {
        float4 v = p4[(size_t)n * (NROWS / 4) + r4];
        s.x += v.x; s.y += v.y; s.z += v.z; s.w += v.w;
    }
    ((float4*)out)[r4] = s;
}

__global__ __launch_bounds__(NT, 4)   // <=128 VGPR -> 2 blocks/CU (LDS-bound)
void hdmr_fused(const float* __restrict__ x, const float* __restrict__ f0p,
    const float* __restrict__ Wi1, const float* __restrict__ bi1,
    const float* __restrict__ bh1, const float* __restrict__ bo1,
    const float* __restrict__ Wi2, const float* __restrict__ bi2,
    const float* __restrict__ bh2, const float* __restrict__ bo2,
    const float* __restrict__ Wi3, const float* __restrict__ bi3,
    const float* __restrict__ bh3, const float* __restrict__ bo3,
    const f16* __restrict__ Whf, const f16* __restrict__ WoF,
    float* __restrict__ part)
{
    __shared__ __attribute__((aligned(16))) char actb[2][BM * HID * 2]; // 64KB ping-pong
    __shared__ __attribute__((aligned(16))) float xrT[2][8 * BM];       // 8KB x tiles, TRANSPOSED [var][row]
    __shared__ __attribute__((aligned(16))) float4 wi4[HID];            // (w0,w1,w2,bias) per col, bank-spread perm

    const int tid = threadIdx.x;
    const int bid = blockIdx.x;
    const int swz = (bid & 7) * (NBLK / 8) + (bid >> 3);   // bijective XCD swizzle
    const int N = swz >> 4;            // network id 0..91
    const int grp = swz & (GRPS - 1);
    const int m_base = grp * (TPB * BM);

    int din, lidx;
    const float *Wi, *bi, *bh, *bo;
    if (N < 8)       { lidx = N;      din = 1; Wi=Wi1; bi=bi1; bh=bh1; bo=bo1; }
    else if (N < 36) { lidx = N - 8;  din = 2; Wi=Wi2; bi=bi2; bh=bh2; bo=bo2; }
    else             { lidx = N - 36; din = 3; Wi=Wi3; bi=bi3; bh=bh3; bo=bo3; }
    Wi += (size_t)lidx * HID * din;
    bi += (size_t)lidx * HID;
    bh += (size_t)lidx * 2 * HID;
    const float bout = bo[lidx];
    const float coef = COEF_C[N];
    const float f0c = (N == 0) ? 35.0f * f0p[0] : 0.0f;
    const f16* WN = Whf + (size_t)N * (2 * HID * HID);
    float* partN = part + (size_t)N * NROWS + m_base;

    const int lane = tid & 63;
    const int wv = tid >> 6;           // 8 waves
    const int lr = lane & 15;
    const int lk = lane >> 4;          // 0..3
    const int C0 = wv * 16;            // this wave's 16-col (j) slice; also its 16-row band

    // ---- permanent register state: hidden/output weight fragments ----
    f16x8 wA0[4], wA1[4], wOut[4];
    #pragma unroll
    for (int kt = 0; kt < 4; ++kt) {
        wA0[kt] = *(const f16x8*)(WN + (size_t)(C0 + lr) * HID + kt * 32 + lk * 8);
        wA1[kt] = *(const f16x8*)(WN + HID * HID + (size_t)(C0 + lr) * HID + kt * 32 + lk * 8);
        wOut[kt] = *(const f16x8*)(WoF + (size_t)N * HID + kt * 32 + lk * 8);
    }
    f32x4 bias0 = *(const f32x4*)(bh + C0 + lk * 4);
    f32x4 bias1 = *(const f32x4*)(bh + HID + C0 + lk * 4);
    #pragma unroll
    for (int i = 0; i < 4; ++i) { bias0[i] *= -LOG2E; bias1[i] *= -LOG2E; }

    const int v0 = VARS_C[N][0];
    const int v1 = VARS_C[N][1] < 0 ? 0 : VARS_C[N][1];
    const int v2 = VARS_C[N][2] < 0 ? 0 : VARS_C[N][2];

    // ---- stage input-layer weights: col c -> wi4[perm(c)], perm = q*8 + j*4 + lk
    //      (c = lk*32 + q*2 + j). Read side wi4[q*8+j*4+lk] puts the 4 lk-broadcast
    //      groups in 4 distinct bank groups -> conflict-free.
    if (tid < HID) {
        const int plk = tid >> 5, rem = tid & 31;
        const int pidx = (rem >> 1) * 8 + (rem & 1) * 4 + plk;
        float4 wv4;
        wv4.x = -LOG2E * Wi[tid * din];
        wv4.y = (din > 1) ? -LOG2E * Wi[tid * din + 1] : 0.0f;
        wv4.z = (din > 2) ? -LOG2E * Wi[tid * din + 2] : 0.0f;
        wv4.w = -LOG2E * bi[tid];
        wi4[pidx] = wv4;
    }
    // ---- stage first x tile, transposed: xrT[var][row] ----
    if (tid < 256) {
        const int m = tid >> 1, half = tid & 1;
        float4 xv = ((const float4*)(x + (size_t)m_base * 8))[tid];
        xrT[0][(half * 4 + 0) * BM + m] = xv.x;
        xrT[0][(half * 4 + 1) * BM + m] = xv.y;
        xrT[0][(half * 4 + 2) * BM + m] = xv.z;
        xrT[0][(half * 4 + 3) * BM + m] = xv.w;
    }
    __syncthreads();

    f32x4 acc[8];

    for (int t = 0; t < TPB; ++t) {
        const int p = t & 1;
        // ======== phase A: output MFMA for tile t-1 (buf p^1) + input layer t (buf p) ========
        f32x4 acco = (f32x4){0.f, 0.f, 0.f, 0.f};
        if (t > 0) {
            #pragma unroll
            for (int kt = 0; kt < 4; ++kt) {
                f16x8 bfr = *(const f16x8*)(actb[p ^ 1] + actoff(C0 + lr, (kt * 32 + lk * 8) * 2));
                acco = __builtin_amdgcn_mfma_f32_16x16x32_f16(wOut[kt], bfr, acco, 0, 0, 0);
            }
        }
        {   // input layer: this wave's 16-row band, lane covers row C0+lr, cols lk*32..+32.
            // x reads: xrT[v][C0+lr] -> 16 consecutive banks, 4-lane broadcast, conflict-free.
            // weight reads: wi4[q*8+j*4+lk] -> 4 distinct bank groups, 16-lane broadcast, conflict-free.
            const int r = C0 + lr;
            const float x0 = xrT[p][v0 * BM + r];
            const float x1 = xrT[p][v1 * BM + r];
            const float x2 = xrT[p][v2 * BM + r];
            f16x8 pk[4];
            #pragma unroll
            for (int q = 0; q < 16; ++q) {
                float4 fA = wi4[q * 8 + lk];
                float4 fB = wi4[q * 8 + 4 + lk];
                float sA = fA.w + x0 * fA.x + x1 * fA.y + x2 * fA.z;
                float sB = fB.w + x0 * fB.x + x1 * fB.y + x2 * fB.z;
                pk[q >> 2][(q & 3) * 2]     = (f16)sig2(sA);
                pk[q >> 2][(q & 3) * 2 + 1] = (f16)sig2(sB);
            }
            #pragma unroll
            for (int qq = 0; qq < 4; ++qq)
                *(f16x8*)(actb[p] + actoff(r, (lk * 32 + qq * 8) * 2)) = pk[qq];
        }
        if (t > 0 && lk == 0) {
            // D[j][m]: wout replicated over j -> every lane holds out[m=lr]; lanes lk==0 commit.
            partN[(t - 1) * BM + C0 + lr] = coef * (acco[0] + bout) - f0c;
        }
        __syncthreads();

        // ======== hidden layer 0: buf p -> buf p^1 ========
        #pragma unroll
        for (int mt = 0; mt < 8; ++mt) acc[mt] = bias0;
        #pragma unroll
        for (int kt = 0; kt < 4; ++kt) {
            const int kb = (kt * 32 + lk * 8) * 2;
            #pragma unroll
            for (int mh = 0; mh < 2; ++mh) {   // halves to limit live bfr regs
                f16x8 bfr[4];
                #pragma unroll
                for (int mi = 0; mi < 4; ++mi)
                    bfr[mi] = *(const f16x8*)(actb[p] + actoff((mh * 4 + mi) * 16 + lr, kb));
                #pragma unroll
                for (int mi = 0; mi < 4; ++mi)
                    acc[mh * 4 + mi] = __builtin_amdgcn_mfma_f32_16x16x32_f16(wA0[kt], bfr[mi], acc[mh * 4 + mi], 0, 0, 0);
            }
        }
        // prefetch next x tile (transposed) while MFMAs drain
        if (t + 1 < TPB && tid < 256) {
            const int m = tid >> 1, half = tid & 1;
            float4 xv = ((const float4*)(x + (size_t)(m_base + (t + 1) * BM) * 8))[tid];
            xrT[p ^ 1][(half * 4 + 0) * BM + m] = xv.x;
            xrT[p ^ 1][(half * 4 + 1) * BM + m] = xv.y;
            xrT[p ^ 1][(half * 4 + 2) * BM + m] = xv.z;
            xrT[p ^ 1][(half * 4 + 3) * BM + m] = xv.w;
        }
        #pragma unroll
        for (int mt = 0; mt < 8; ++mt) {
            f16x4 hv;
            #pragma unroll
            for (int i = 0; i < 4; ++i) hv[i] = (f16)sig2(acc[mt][i]);
            *(f16x4*)(actb[p ^ 1] + actoff(mt * 16 + lr, (C0 + lk * 4) * 2)) = hv;
        }
        __syncthreads();

        // ======== hidden layer 1: buf p^1 -> buf p ========
        #pragma unroll
        for (int mt = 0; mt < 8; ++mt) acc[mt] = bias1;
        #pragma unroll
        for (int kt = 0; kt < 4; ++kt) {
            const int kb = (kt * 32 + lk * 8) * 2;
            #pragma unroll
            for (int mh = 0; mh < 2; ++mh) {
                f16x8 bfr[4];
                #pragma unroll
                for (int mi = 0; mi < 4; ++mi)
                    bfr[mi] = *(const f16x8*)(actb[p ^ 1] + actoff((mh * 4 + mi) * 16 + lr, kb));
                #pragma unroll
                for (int mi = 0; mi < 4; ++mi)
                    acc[mh * 4 + mi] = __builtin_amdgcn_mfma_f32_16x16x32_f16(wA1[kt], bfr[mi], acc[mh * 4 + mi], 0, 0, 0);
            }
        }
        #pragma unroll
        for (int mt = 0; mt < 8; ++mt) {
            f16x4 hv;
            #pragma unroll
            for (int i = 0; i < 4; ++i) hv[i] = (f16)sig2(acc[mt][i]);
            *(f16x4*)(actb[p] + actoff(mt * 16 + lr, (C0 + lk * 4) * 2)) = hv;
        }
        __syncthreads();
    }

    // ======== final output for tile TPB-1 (act in buf[(TPB-1)&1] = buf 1) ========
    {
        f32x4 acco = (f32x4){0.f, 0.f, 0.f, 0.f};
        #pragma unroll
        for (int kt = 0; kt < 4; ++kt) {
            f16x8 bfr = *(const f16x8*)(actb[1] + actoff(C0 + lr, (kt * 32 + lk * 8) * 2));
            acco = __builtin_amdgcn_mfma_f32_16x16x32_f16(wOut[kt], bfr, acco, 0, 0, 0);
        }
        if (lk == 0)
            partN[(TPB - 1) * BM + C0 + lr] = coef * (acco[0] + bout) - f0c;
    }
}

extern "C" void kernel_launch(void* const* d_in, const int* in_sizes, int n_in,
                              void* d_out, int out_size, void* d_ws, size_t ws_size,
                              hipStream_t stream) {
    const float* x   = (const float*)d_in[0];
    const float* f0  = (const float*)d_in[1];
    const float* Wi1 = (const float*)d_in[2];
    const float* bi1 = (const float*)d_in[3];
    const float* Wh1 = (const float*)d_in[4];
    const float* bh1 = (const float*)d_in[5];
    const float* Wo1 = (const float*)d_in[6];
    const float* bo1 = (const float*)d_in[7];
    const float* Wi2 = (const float*)d_in[8];
    const float* bi2 = (const float*)d_in[9];
    const float* Wh2 = (const float*)d_in[10];
    const float* bh2 = (const float*)d_in[11];
    const float* Wo2 = (const float*)d_in[12];
    const float* bo2 = (const float*)d_in[13];
    const float* Wi3 = (const float*)d_in[14];
    const float* bi3 = (const float*)d_in[15];
    const float* Wh3 = (const float*)d_in[16];
    const float* bh3 = (const float*)d_in[17];
    const float* Wo3 = (const float*)d_in[18];
    const float* bo3 = (const float*)d_in[19];
    float* out = (float*)d_out;

    f16* Whf = (f16*)d_ws;                       // ~5.8 MB scaled hidden weights
    f16* WoF = Whf + SW;                         // +23 KB output weights
    float* part = (float*)(Whf + SW + 16384);    // 92*8192*4B = 3 MB partials (16KB pad keeps alignment)

    hipLaunchKernelGGL(cvt_w, dim3((CVT_TOTAL / 4 + 255) / 256), dim3(256), 0, stream,
                       Wh1, Wh2, Wh3, Wo1, Wo2, Wo3, Whf);
    hipLaunchKernelGGL(hdmr_fused, dim3(NBLK), dim3(NT), 0, stream,
                       x, f0, Wi1, bi1, bh1, bo1,
                       Wi2, bi2, bh2, bo2,
                       Wi3, bi3, bh3, bo3, Whf, WoF, part);
    hipLaunchKernelGGL(reduce_out, dim3(NROWS / 4 / 128), dim3(128), 0, stream,
                       part, out);
}